// Round 15
// baseline (39.735 us; speedup 1.0000x reference)
//
#include <hip/hip_runtime.h>

// ---------------------------------------------------------------------------
// FFT_Conv_Layer == 3x3 "same" spatial conv with flipped REAL filter plane.
//
// Ladder: R2 22.54 | R7 21.24 (swz) | R8 21.07 | R9 21.10 | R10 21.55 |
//         R13 23.98 (prep round-trip +2.9us). Six levers neutral; bottom-up
//         floor ~7-8us vs 21 measured => ~13us unexplained, and conv's
//         counters have NEVER been visible (ws-poison fills clog top-5).
// R14 DIAGNOSTIC (resubmitted after container failure): repeat [K-loop+store]
// 6x (identical stores; unroll-1 loop, per-rep barrier blocks LDS-read CSE).
// Makes conv ~45-55us -> visible in top-5, and (dur-21.2)/5 = true marginal
// K+store cost. Decision rule:
//   dV~6us  -> overhead-bound -> fuse to 1 dispatch next.
//   dV~12+  -> K-loop stalls  -> preload 36 B-frags to regs next.
// ---------------------------------------------------------------------------

typedef _Float16 f16x8 __attribute__((ext_vector_type(8)));
typedef float    f32x4 __attribute__((ext_vector_type(4)));

#define NB 16
#define NC 64
#define NH 64
#define NW 64
#define CHUNKS 528                 // 66 xp positions * 8 channel-chunks per slab
#define SLAB_BYTES (CHUNKS * 16)   // 8448 B per image row slab
#define WF_HALFS (9 * 2 * 4 * 64 * 8)  // 36,864
#define REPS 6

// ---------------------------------------------------------------------------
// prep_w: filts [1][inC][outC][3][3][2] f32 -> per-fragment f16 weights
// ---------------------------------------------------------------------------
__global__ __launch_bounds__(256) void prep_w(const float* __restrict__ filts,
                                              _Float16* __restrict__ wf) {
    const int f = blockIdx.x * 256 + threadIdx.x;
    if (f >= WF_HALFS) return;
    const int e  = f & 7;
    const int l  = (f >> 3) & 63;
    const int n  = (f >> 9) & 3;
    const int kc = (f >> 11) & 1;
    const int t  = f >> 12;              // 0..8
    const int i  = kc * 32 + (l >> 4) * 8 + e;
    const int o  = n * 16 + (l & 15);
    const int ky = t / 3, kx = t % 3;
    wf[f] = (_Float16)filts[(((i * 64 + o) * 3 + ky) * 3 + kx) * 2];
}

// ---------------------------------------------------------------------------
// conv_direct (R7 structure, [K-loop+store] repeated REPS times).
// ---------------------------------------------------------------------------
__global__ __launch_bounds__(256, 2) void conv_direct(const float* __restrict__ imgs,
                                                      const _Float16* __restrict__ wf,
                                                      float* __restrict__ out) {
    __shared__ uint4 ldsb[4 * SLAB_BYTES / 16];   // 33,792 B
    char* lds = reinterpret_cast<char*>(ldsb);
    const int bid = blockIdx.x;
    const int swz = ((bid & 7) << 6) | (bid >> 3);   // bijective: 512 = 8*64
    const int b   = swz >> 5;
    const int y0  = (swz & 31) << 1;
    const int tid = threadIdx.x;
    const int w   = tid >> 6;
    const int l   = tid & 63;
    const int h   = l >> 4;
    const int r   = l & 15;

    // ---- stage slab w = image row y0 + w - 1 (once) ----
    {
        const int y  = y0 + w - 1;
        const bool yv = ((unsigned)y < (unsigned)NH);
        char* slab = lds + w * SLAB_BYTES;
        if (l < 16) {
            const int ci  = l >> 1;
            const int xp2 = (l & 1) ? 65 : 0;
            const int c2  = xp2 * 8 + (ci ^ (xp2 & 7));
            f16x8 z;
            #pragma unroll
            for (int k = 0; k < 8; ++k) z[k] = (_Float16)0.f;
            *reinterpret_cast<f16x8*>(slab + c2 * 16) = z;
        }
        float f[64];
        if (yv) {
            const float* src = imgs + (((size_t)(b * NC)) * NH + y) * NW + l;
            #pragma unroll
            for (int c = 0; c < 64; ++c) f[c] = src[(size_t)c * NH * NW];
        } else {
            #pragma unroll
            for (int c = 0; c < 64; ++c) f[c] = 0.f;
        }
        const int xp = l + 1;
        #pragma unroll
        for (int ci = 0; ci < 8; ++ci) {
            f16x8 v;
            #pragma unroll
            for (int k = 0; k < 8; ++k) v[k] = (_Float16)f[ci * 8 + k];
            const int chunk = xp * 8 + (ci ^ (xp & 7));
            *reinterpret_cast<f16x8*>(slab + chunk * 16) = v;
        }
    }

    const int row = w >> 1;
    const int oh  = w & 1;
    const int y   = y0 + row;

    #pragma unroll 1
    for (int rep = 0; rep < REPS; ++rep) {
        __syncthreads();                 // orders LDS reads; defeats cross-rep CSE

        f32x4 acc[4][2];
        #pragma unroll
        for (int m = 0; m < 4; ++m)
            #pragma unroll
            for (int n = 0; n < 2; ++n)
                acc[m][n] = f32x4{0.f, 0.f, 0.f, 0.f};

        #pragma unroll
        for (int ky = 0; ky < 3; ++ky) {
            const char* slab = lds + (row + 2 - ky) * SLAB_BYTES;
            #pragma unroll
            for (int kx = 0; kx < 3; ++kx) {
                const _Float16* wft = wf + (size_t)(ky * 3 + kx) * (2 * 4 * 64 * 8);
                #pragma unroll
                for (int kc = 0; kc < 2; ++kc) {
                    f16x8 a[4], bb[2];
                    #pragma unroll
                    for (int m = 0; m < 4; ++m) {
                        const int xp = m * 16 + r + 2 - kx;
                        const int chunk = xp * 8 + (((kc << 2) + h) ^ (xp & 7));
                        a[m] = *reinterpret_cast<const f16x8*>(slab + chunk * 16);
                    }
                    #pragma unroll
                    for (int n = 0; n < 2; ++n)
                        bb[n] = *reinterpret_cast<const f16x8*>(
                            wft + ((size_t)((kc << 2) + (oh * 2 + n)) * 64 + l) * 8);
                    #pragma unroll
                    for (int m = 0; m < 4; ++m)
                        #pragma unroll
                        for (int n = 0; n < 2; ++n)
                            acc[m][n] = __builtin_amdgcn_mfma_f32_16x16x32_f16(a[m], bb[n], acc[m][n], 0, 0, 0);
                }
            }
        }

        #pragma unroll
        for (int m = 0; m < 4; ++m) {
            const int x0 = m * 16 + h * 4;
            #pragma unroll
            for (int n = 0; n < 2; ++n) {
                const int o = oh * 32 + n * 16 + r;
                *reinterpret_cast<f32x4*>(out + (((size_t)(b * 64 + o) * 64 + y) * 64) + x0) = acc[m][n];
            }
        }
    }
}

extern "C" void kernel_launch(void* const* d_in, const int* in_sizes, int n_in,
                              void* d_out, int out_size, void* d_ws, size_t ws_size,
                              hipStream_t stream) {
    const float* imgs  = (const float*)d_in[0];   // [16][64][64][64] f32
    const float* filts = (const float*)d_in[1];   // [1][64][64][3][3][2] f32
    float* out = (float*)d_out;                   // [16][64][64][64] f32
    _Float16* wfb = (_Float16*)d_ws;              // 73,728 B only

    hipLaunchKernelGGL(prep_w, dim3((WF_HALFS + 255) / 256), dim3(256), 0, stream, filts, wfb);
    hipLaunchKernelGGL(conv_direct, dim3(NB * 32), dim3(256), 0, stream, imgs, wfb, out);
}